// Round 10
// baseline (195.053 us; speedup 1.0000x reference)
//
#include <hip/hip_runtime.h>
#include <hip/hip_bf16.h>
#include <math.h>

typedef __hip_bfloat16 bf16;
typedef __attribute__((ext_vector_type(8))) short short8;
typedef __attribute__((ext_vector_type(4))) float floatx4;

#define D_MODEL 1024
#define NUM_HEADS 16
#define DK 64
#define SEQ 2048
#define BATCH 2
#define MROWS (BATCH * SEQ)          // 4096
#define KDIM 1024
#define SEG_X ((size_t)MROWS * D_MODEL)      // 4194304
#define SEG_W ((size_t)D_MODEL * D_MODEL)    // 1048576
#define QKSTRIDE 2048                         // fused Q|K row stride
#define ROPE_C (-9.2103403719761836f / 64.f)  // -ln(10000)/dk
// Q prescale: dk^-0.5 * log2(e)  -> scores arrive in log2 domain, P = exp2(S)
#define QSCALE (0.125f * 1.4426950408889634f)

__device__ inline void gload16(const void* g, void* l) {
    __builtin_amdgcn_global_load_lds(
        (const __attribute__((address_space(1))) void*)g,
        (__attribute__((address_space(3))) void*)l, 16, 0, 0);
}

// ---------------------------------------------------------------------------
// Cast fp32 inputs to bf16 workspace buffers.
// ---------------------------------------------------------------------------
__global__ __launch_bounds__(256) void cast_kernel(
    const float* __restrict__ x,  const float* __restrict__ Wq,
    const float* __restrict__ Wk, const float* __restrict__ Wv,
    const float* __restrict__ Wo,
    bf16* __restrict__ xb, bf16* __restrict__ w_all, bf16* __restrict__ wob)
{
    const size_t i = ((size_t)blockIdx.x * 256 + threadIdx.x) * 4;
    const float* src; bf16* dst;
    if (i < SEG_X)                    { src = x  + i;                       dst = xb + i; }
    else if (i < SEG_X + SEG_W)       { src = Wq + (i - SEG_X);             dst = w_all + (i - SEG_X); }
    else if (i < SEG_X + 2 * SEG_W)   { src = Wk + (i - SEG_X - SEG_W);     dst = w_all + (i - SEG_X); }
    else if (i < SEG_X + 3 * SEG_W)   { src = Wv + (i - SEG_X - 2 * SEG_W); dst = w_all + (i - SEG_X); }
    else                              { src = Wo + (i - SEG_X - 3 * SEG_W); dst = wob + (i - SEG_X - 3 * SEG_W); }
    float4 v = *reinterpret_cast<const float4*>(src);
    __hip_bfloat162 lo, hi;
    lo.x = __float2bfloat16(v.x); lo.y = __float2bfloat16(v.y);
    hi.x = __float2bfloat16(v.z); hi.y = __float2bfloat16(v.w);
    __hip_bfloat162* d2 = reinterpret_cast<__hip_bfloat162*>(dst);
    d2[0] = lo; d2[1] = hi;
}

// ---------------------------------------------------------------------------
// GEMM: 128x128 tile, 4 waves (256 thr), ROUND-10: BK=32 QUAD-BUFFERED LDS
// (4 x 16 KB = 64 KB, unchanged -> 2 blocks/CU) with depth-2 counted-vmcnt
// pipeline (T4):
//     stage(t+2) -> s_waitcnt vmcnt(8) -> s_barrier -> compute(t)
//   Round-9 accounting: the old 2-phase __syncthreads (= vmcnt(0) drain)
//   exposed ~1700 cy/step of load latency (step 3150 cy vs 640 MFMA + 770
//   ds_read).  Now each stage batch has TWO full steps to land and the
//   barrier never drains the newest loads (vmcnt(8) = 2 batches in flight).
//   Hazards: WAR -- stage(t+2) overwrites the buffer compute(t-2) read, >=1
//   barrier back for all waves; RAW -- vmcnt(8)+barrier ensures all waves'
//   stage(t) landed.  Live set ~116 regs (unchanged, < 128 budget).
//   LDS swizzle (rounds 1-9, measured 0 conflicts): source granule g of row
//   r=g>>2 holds global k-chunk (g&3)^((r>>1)&3); read chunk lq^((r>>1)&3).
// IS_PROJ: fused RoPE (Q prescaled) -> qkb, V transposed -> vtb.
// else:    plain fp32 C store (output projection).
// ---------------------------------------------------------------------------
template <bool IS_PROJ>
__global__ __launch_bounds__(256) void gemm128_kernel(
    const bf16* __restrict__ A, const bf16* __restrict__ W,
    bf16* __restrict__ qkb, bf16* __restrict__ vtb,
    float* __restrict__ C, const int* __restrict__ pos)
{
    // [4 bufs][128 rows x 32 k], row stride 32 bf16 = 64 B
    __shared__ bf16 As[4][128 * 32];
    __shared__ bf16 Bs[4][128 * 32];

    const int tileM = blockIdx.x * 128;
    const int tileN = blockIdx.y * 128;
    const int tid = threadIdx.x;
    const int w = tid >> 6, lane = tid & 63;
    const int wm = (w & 1) * 64, wn = (w >> 1) * 64;   // 2x2 waves of 64x64
    const int l15 = lane & 15, lq = lane >> 4;
    const bool isV = IS_PROJ && (tileN >= 2048);

    floatx4 acc[4][4];
    #pragma unroll
    for (int a = 0; a < 4; ++a)
        #pragma unroll
        for (int b = 0; b < 4; ++b)
            acc[a][b] = (floatx4){0.f, 0.f, 0.f, 0.f};

    // one K-step = 128 rows x 32 k per matrix = 8 KB = 2 gload16/thread each
    auto stage = [&](int buf, int kb) {
        #pragma unroll
        for (int i = 0; i < 2; ++i) {
            const int g = i * 256 + tid;     // granule 0..511
            const int r = g >> 2;            // row 0..127
            const int c = ((g & 3) ^ ((r >> 1) & 3)) * 8;  // swizzled src
            const int dst = (i * 256 + (tid & 0xC0)) * 8;  // linear dest
            gload16(A + (size_t)(tileM + r) * KDIM + kb + c, &As[buf][dst]);
            gload16(W + (size_t)(tileN + r) * KDIM + kb + c, &Bs[buf][dst]);
        }
    };

    auto compute = [&](int buf) {
        short8 af[4], bfr[4];
        #pragma unroll
        for (int mt = 0; mt < 4; ++mt) {
            const int r = wm + mt * 16 + l15;
            af[mt] = *reinterpret_cast<const short8*>(
                &As[buf][r * 32 + (lq ^ ((r >> 1) & 3)) * 8]);
        }
        #pragma unroll
        for (int nt = 0; nt < 4; ++nt) {
            const int r = wn + nt * 16 + l15;
            bfr[nt] = *reinterpret_cast<const short8*>(
                &Bs[buf][r * 32 + (lq ^ ((r >> 1) & 3)) * 8]);
        }
        if (isV) {
            #pragma unroll
            for (int mt = 0; mt < 4; ++mt)
                #pragma unroll
                for (int nt = 0; nt < 4; ++nt)
                    acc[mt][nt] = __builtin_amdgcn_mfma_f32_16x16x32_bf16(
                        bfr[nt], af[mt], acc[mt][nt], 0, 0, 0);
        } else {
            #pragma unroll
            for (int mt = 0; mt < 4; ++mt)
                #pragma unroll
                for (int nt = 0; nt < 4; ++nt)
                    acc[mt][nt] = __builtin_amdgcn_mfma_f32_16x16x32_bf16(
                        af[mt], bfr[nt], acc[mt][nt], 0, 0, 0);
        }
    };

    const int NT = KDIM / 32;  // 32 K-steps
    stage(0, 0);
    stage(1, 32);

    for (int t = 0; t < NT; ++t) {
        if (t + 2 < NT) {
            stage((t + 2) & 3, (t + 2) * 32);
            asm volatile("s_waitcnt vmcnt(8)" ::: "memory");   // stage(t) done
        } else if (t + 1 < NT) {
            asm volatile("s_waitcnt vmcnt(4)" ::: "memory");
        } else {
            asm volatile("s_waitcnt vmcnt(0)" ::: "memory");
        }
        __builtin_amdgcn_s_barrier();
        __builtin_amdgcn_sched_barrier(0);
        compute(t & 3);
    }

    // --- epilogues (C/D layout: col = l15, row = lq*4 + reg)
    if (!IS_PROJ) {
        #pragma unroll
        for (int mt = 0; mt < 4; ++mt) {
            #pragma unroll
            for (int nt = 0; nt < 4; ++nt) {
                const int col = tileN + wn + nt * 16 + l15;
                #pragma unroll
                for (int r = 0; r < 4; ++r) {
                    const int row = tileM + wm + mt * 16 + lq * 4 + r;
                    C[(size_t)row * D_MODEL + col] = acc[mt][nt][r];
                }
            }
        }
    } else if (!isV) {
        const float qscale = (tileN < 1024) ? QSCALE : 1.0f;
        const int p64 = (pos[1] == 0);
        #pragma unroll
        for (int mt = 0; mt < 4; ++mt) {
            #pragma unroll
            for (int nt = 0; nt < 4; ++nt) {
                const int colg = tileN + wn + nt * 16 + l15;
                const int ip = (colg & 63) >> 1;
                const float freq = __expf((float)(2 * ip) * ROPE_C);
                #pragma unroll
                for (int r = 0; r < 4; ++r) {
                    const int row = tileM + wm + mt * 16 + lq * 4 + r;
                    const int s = row & (SEQ - 1);
                    const int ptok = p64 ? pos[2 * s] : pos[s];
                    const float v = acc[mt][nt][r];
                    const float pv = __shfl_xor(v, 1);
                    const float ang = (float)ptok * freq;
                    const float sn = __sinf(ang), cs = __cosf(ang);
                    const float outv = ((colg & 1) ? fmaf(pv, sn, v * cs)
                                                   : (v * cs - pv * sn)) * qscale;
                    qkb[(size_t)row * QKSTRIDE + colg] = __float2bfloat16(outv);
                }
            }
        }
    } else {
        // swapped-operand V tile: reg index = N (v-col), l15 = M (seq row)
        const int bq = tileM >> 11;
        const int tnoff = tileN - 2048;
        #pragma unroll
        for (int mt = 0; mt < 4; ++mt) {
            const int s = (tileM & (SEQ - 1)) + wm + mt * 16 + l15;
            #pragma unroll
            for (int nt = 0; nt < 4; ++nt) {
                #pragma unroll
                for (int r = 0; r < 4; ++r) {
                    const int vcol = tnoff + wn + nt * 16 + lq * 4 + r;
                    const int bh = bq * 16 + (vcol >> 6);
                    const int d = vcol & 63;
                    vtb[((size_t)bh * 64 + d) * SEQ + s] =
                        __float2bfloat16(acc[mt][nt][r]);
                }
            }
        }
    }
}

// ---------------------------------------------------------------------------
// MFMA flash attention (round-9 state, unchanged): paired q-tiles, shared-bv
// PV, stride-40 Ps, XCD remap (FETCH 62->12 MB), gemm-proven K/V swizzle
// (conflicts 5.9M -> <3.75M over rounds 6-9), setprio.
// ---------------------------------------------------------------------------
__global__ __launch_bounds__(256) void flash_attn_kernel(
    const bf16* __restrict__ qk, const bf16* __restrict__ vtb,
    bf16* __restrict__ O)
{
    __shared__ bf16 Ks[2][2][64][32];      // [buf][panel][row][32]
    __shared__ bf16 Vt[2][2][64][32];
    __shared__ bf16 Ps[8][2][16][40];      // [region][kp][row][40-pad]

    const int lin = blockIdx.y * 16 + blockIdx.x;          // 0..511
    const int bh  = (lin & 7) + 8 * ((lin >> 3) & 3);      // 4 bh per XCD
    const int qtA = lin >> 5;            // 0..15
    const int qtB = 31 - qtA;            // 31..16
    const int b = bh >> 4, h = bh & 15;
    const int t = threadIdx.x;
    const int w = t >> 6, lane = t & 63;
    const int l15 = lane & 15, lq = lane >> 4;

    const bf16* qbase = qk + (size_t)b * SEQ * QKSTRIDE + h * 64;
    const bf16* kbase = qbase + 1024;
    const bf16* vbase = vtb + (size_t)bh * 64 * SEQ;

    short8 aqA[2], aqB[2];
    {
        const bf16* qr = qbase + (size_t)(qtA * 64 + 16 * w + l15) * QKSTRIDE;
        aqA[0] = *reinterpret_cast<const short8*>(qr + lq * 8);
        aqA[1] = *reinterpret_cast<const short8*>(qr + 32 + lq * 8);
        qr = qbase + (size_t)(qtB * 64 + 16 * w + l15) * QKSTRIDE;
        aqB[0] = *reinterpret_cast<const short8*>(qr + lq * 8);
        aqB[1] = *reinterpret_cast<const short8*>(qr + 32 + lq * 8);
    }

    const int srow = lane >> 2;
    const int scol = (((lane & 3) ^ ((lane >> 3) & 3))) * 8;  // staging swizzle
    const int rsw = lq ^ ((l15 >> 1) & 3);                    // K/V frag read
    const int psw = lq ^ (l15 >> 2);                          // Ps frag read

    const short8 ones8 = {0x3F80, 0x3F80, 0x3F80, 0x3F80,
                          0x3F80, 0x3F80, 0x3F80, 0x3F80};  // bf16 1.0 x8

    floatx4 accA[4], accB[4], lAcc[2];
    #pragma unroll
    for (int nt = 0; nt < 4; ++nt) {
        accA[nt] = (floatx4){0.f, 0.f, 0.f, 0.f};
        accB[nt] = (floatx4){0.f, 0.f, 0.f, 0.f};
    }
    lAcc[0] = (floatx4){0.f, 0.f, 0.f, 0.f};
    lAcc[1] = (floatx4){0.f, 0.f, 0.f, 0.f};

    const int rowloc = 16 * w + lq * 4;

    // exp2 + swizzled Ps store into region 'reg' (stride-40 scheme, r6-proven)
    auto exp_store = [&](floatx4* accS, bool diag, int reg) {
        #pragma unroll
        for (int nt = 0; nt < 4; ++nt) {
            const int colloc = nt * 16 + l15;
            #pragma unroll
            for (int r = 0; r < 4; ++r) {
                float e = __builtin_amdgcn_exp2f(accS[nt][r]);
                if (diag && colloc > rowloc + r) e = 0.f;
                Ps[reg][nt >> 1][lq * 4 + r]
                  [((((nt & 1) * 2 + (l15 >> 3)) ^ lq) * 8) + (l15 & 7)] =
                    __float2bfloat16(e);
            }
        }
    };

    auto stage = [&](int kt, int buf) {
        #pragma unroll
        for (int p = 0; p < 2; ++p) {
            gload16(kbase + (size_t)(kt * 64 + 16 * w + srow) * QKSTRIDE
                        + p * 32 + scol,
                    &Ks[buf][p][16 * w][0]);
            gload16(vbase + (size_t)(16 * w + srow) * SEQ + kt * 64
                        + p * 32 + scol,
                    &Vt[buf][p][16 * w][0]);
        }
    };

    stage(0, 0);
    __syncthreads();

    for (int kt = 0; kt <= qtB; ++kt) {
        const int cur = kt & 1;
        if (kt < qtB) stage(kt + 1, cur ^ 1);

        short8 bk[2][4];
        #pragma unroll
        for (int p = 0; p < 2; ++p)
            #pragma unroll
            for (int nt = 0; nt < 4; ++nt)
                bk[p][nt] = *reinterpret_cast<const short8*>(
                    &Ks[cur][p][nt * 16 + l15][rsw * 8]);

        __builtin_amdgcn_s_setprio(1);
        floatx4 sB[4];
        #pragma unroll
        for (int nt = 0; nt < 4; ++nt) sB[nt] = (floatx4){0.f, 0.f, 0.f, 0.f};
        #pragma unroll
        for (int p = 0; p < 2; ++p)
            #pragma unroll
            for (int nt = 0; nt < 4; ++nt)
                sB[nt] = __builtin_amdgcn_mfma_f32_16x16x32_bf16(
                    aqB[p], bk[p][nt], sB[nt], 0, 0, 0);
        __builtin_amdgcn_s_setprio(0);

        if (kt <= qtA) {
            // --- paired path: both tiles active; shared-bv PV
            __builtin_amdgcn_s_setprio(1);
            floatx4 sA[4];
            #pragma unroll
            for (int nt = 0; nt < 4; ++nt) sA[nt] = (floatx4){0.f, 0.f, 0.f, 0.f};
            #pragma unroll
            for (int p = 0; p < 2; ++p)
                #pragma unroll
                for (int nt = 0; nt < 4; ++nt)
                    sA[nt] = __builtin_amdgcn_mfma_f32_16x16x32_bf16(
                        aqA[p], bk[p][nt], sA[nt], 0, 0, 0);
            __builtin_amdgcn_s_setprio(0);

            exp_store(sB, kt == qtB, w);
            exp_store(sA, kt == qtA, w + 4);

            #pragma unroll
            for (int kp = 0; kp < 2; ++kp) {
                const short8 apB = *reinterpret_cast<const short8*>(
                    &Ps[w][kp][l15][psw * 8]);
                const short8 apA = *reinterpret_cast<const short8*>(
                    &Ps[w + 4][kp][l15][psw * 8]);
                short8 bv[4];
                #pragma unroll
                for (int nt = 0; nt < 4; ++nt)
                    bv[nt] = *reinterpret_cast<const short8*>(
                        &Vt[cur][kp][nt * 16 + l15][rsw * 8]);
                __builtin_amdgcn_s_setprio(1);
                #pragma unroll
                for (int nt = 0; nt < 4; ++nt)
                    accB[nt] = __builtin_amdgcn_mfma_f32_16x16x32_bf16(
                        apB, bv[nt], accB[nt], 0, 0, 0);
                lAcc[1] = __builtin_amdgcn_mfma_f32_16x16x32_bf16(
                    apB, ones8, lAcc[1], 0, 0, 0);
                #pragma unroll
                for (int nt = 0; nt < 4; ++nt)
                    accA[nt] = __builtin_amdgcn_mfma_f32_16x16x32_bf16(
                        apA, bv[nt], accA[nt], 0, 0, 0);
                lAcc[0] = __builtin_amdgcn_mfma_f32_16x16x32_bf16(
                    apA, ones8, lAcc[0], 0, 0, 0);
                __builtin_amdgcn_s_setprio(0);
            }
        } else {
            // --- single-tile path (kt > qtA): tile B only
            exp_store(sB, kt == qtB, w);
            #pragma unroll
            for (int kp = 0; kp < 2; ++kp) {
                const short8 apB = *reinterpret_cast<const short8*>(
                    &Ps[w][kp][l15][psw * 8]);
                __builtin_amdgcn_s_setprio(1);
                #pragma unroll
                for (int nt = 0; nt < 4; ++nt) {
                    const short8 bv = *reinterpret_cast<const short8*>(
                        &Vt[cur][kp][nt * 16 + l15][rsw * 8]);
                    accB[nt] = __builtin_amdgcn_mfma_f32_16x16x32_bf16(
                        apB, bv, accB[nt], 0, 0, 0);
                }
                lAcc[1] = __builtin_amdgcn_mfma_f32_16x16x32_bf16(
                    apB, ones8, lAcc[1], 0, 0, 0);
                __builtin_amdgcn_s_setprio(0);
            }
        }
        __syncthreads();
    }

    // Epilogue: lAcc holds the row sums (replicated across l15).
    auto epilogue = [&](floatx4* accO, floatx4& accL, int qt) {
        #pragma unroll
        for (int r = 0; r < 4; ++r) {
            const float inv = 1.f / accL[r];
            const int qrow = qt * 64 + 16 * w + lq * 4 + r;
            #pragma unroll
            for (int nt = 0; nt < 4; ++nt) {
                O[((size_t)(b * SEQ + qrow)) * D_MODEL + h * DK + nt * 16 + l15] =
                    __float2bfloat16(accO[nt][r] * inv);
            }
        }
    };
    epilogue(accA, lAcc[0], qtA);
    epilogue(accB, lAcc[1], qtB);
}

extern "C" void kernel_launch(void* const* d_in, const int* in_sizes, int n_in,
                              void* d_out, int out_size, void* d_ws, size_t ws_size,
                              hipStream_t stream)
{
    const float* x   = (const float*)d_in[0];
    const int*   pos = (const int*)d_in[1];
    const float* Wq  = (const float*)d_in[2];
    const float* Wk  = (const float*)d_in[3];
    const float* Wv  = (const float*)d_in[4];
    const float* Wo  = (const float*)d_in[5];
    float* out = (float*)d_out;

    bf16* xb    = (bf16*)d_ws;
    bf16* w_all = xb + SEG_X;
    bf16* wob   = w_all + 3 * SEG_W;
    bf16* qkb   = wob + SEG_W;                     // 4096 x 2048 (Q|K roped)
    bf16* vtb   = qkb + (size_t)MROWS * QKSTRIDE;  // 32 bh x 64 d x 2048 s
    bf16* ob    = xb;                              // reuse: x dead after GEMM1

    cast_kernel<<<8192, 256, 0, stream>>>(x, Wq, Wk, Wv, Wo, xb, w_all, wob);
    gemm128_kernel<true><<<dim3(32, 24), 256, 0, stream>>>(
        xb, w_all, qkb, vtb, nullptr, pos);
    flash_attn_kernel<<<dim3(16, 32), 256, 0, stream>>>(qkb, vtb, ob);
    gemm128_kernel<false><<<dim3(32, 8), 256, 0, stream>>>(
        ob, wob, nullptr, nullptr, out, nullptr);
}